// Round 10
// baseline (175.082 us; speedup 1.0000x reference)
//
#include <hip/hip_runtime.h>
#include <hip/hip_bf16.h>

typedef __attribute__((ext_vector_type(8))) short bf16x8;
typedef __attribute__((ext_vector_type(4))) float f32x4;

#define L_SEQ 512
#define N_IN 12
#define S_DIM 128
#define M_OUT 12
#define LPAD 40           // shorts per n-row (80B -> <=2-way banks)
#define KT_STRIDE (16*LPAD)

// RNE f32->bf16 (cold paths)
__device__ inline short f2bf(float f) {
    union { float f; unsigned u; } q; q.f = f;
    unsigned r = (q.u + 0x7fffu + ((q.u >> 16) & 1u)) >> 16;
    return (short)r;
}
// packed f32x2 -> 2xbf16 (RNE), one VALU op
__device__ inline unsigned cvtpk(float lo, float hi) {
    unsigned r;
    asm("v_cvt_pk_bf16_f32 %0, %1, %2" : "=v"(r) : "v"(lo), "v"(hi));
    return r;
}
// B-slot (kt,q,j) holds state row s = 32kt + 16(j>>2) + 4q + (j&3).
// Same-lane D->B chaining: E2E-verified R4/R5/R7/R8.
__device__ inline int s_perm(int kt, int q, int j) {
    return 32 * kt + 16 * (j >> 2) + 4 * q + (j & 3);
}
// lgkm-only barrier: does NOT drain vmcnt (helpers' x prefetch stays in flight)
__device__ inline void block_sync() {
    asm volatile("s_waitcnt lgkmcnt(0)" ::: "memory");
    __builtin_amdgcn_s_barrier();
}

__global__ __launch_bounds__(512, 1)
void elman_kernel(const float* __restrict__ x,
                  const float* __restrict__ a0,
                  const float* __restrict__ U_w,
                  const float* __restrict__ U_b,
                  const float* __restrict__ W_w,
                  const float* __restrict__ W_b,
                  const float* __restrict__ V_w,
                  const float* __restrict__ V_b,
                  float* __restrict__ out)
{
    __shared__ __align__(16) short stx[2][4 * KT_STRIDE];   // state exchange (ping-pong)
    __shared__ __align__(16) float aux[4][4][2][64][4];     // accU ring: [slot][WAVE][h][lane][4]

    const int tid  = threadIdx.x;
    const int w    = tid >> 6;        // waves 0..3 compute, 4..7 accU/x producers
    const int l    = tid & 63;
    const int n    = l & 15;
    const int q    = l >> 4;
    const bool qodd = (q & 1);
    const int b0   = blockIdx.x * 16;
    const int row  = b0 + n;
    const int fragoff = n * LPAD + q * 8;
    const int hw   = w & 3;           // helper's served compute-wave id

    const float* xpA = x + (size_t)row * L_SEQ * N_IN + (q & 1) * 8;
    const float* xpB = xpA + (qodd ? 0 : 4);

#define MAKE_XF(XF, XA, XB) do {                                                       \
    union { unsigned uu[4]; bf16x8 v; } xu_;                                           \
    xu_.uu[0] = cvtpk(XA.x, XA.y);                                                     \
    xu_.uu[1] = cvtpk(XA.z, XA.w);                                                     \
    xu_.uu[2] = qodd ? 0x00003F80u : cvtpk(XB.x, XB.y);  /* k==12 -> bf16(1.0) */      \
    xu_.uu[3] = qodd ? 0u          : cvtpk(XB.z, XB.w);                                \
    XF = xu_.v;                                                                        \
} while (0)

    // ---- step-invariant fragments ----
    // compute wave w: W rows [32w,32w+32) as wf[h][li], physical kt=(w+li)&3
    // helper wave w+4: U rows for compute wave (w&3) as uf[h] (bias folded at k=12)
    bf16x8 wf[2][4]; bf16x8 uf[2];
    if (w < 4) {
        #pragma unroll
        for (int h = 0; h < 2; ++h) {
            const int c = (2 * w + h) * 16 + n;
            #pragma unroll
            for (int li = 0; li < 4; ++li) {
                const int kt = (w + li) & 3;
                #pragma unroll
                for (int j = 0; j < 8; ++j)
                    wf[h][li][j] = f2bf(W_w[(size_t)s_perm(kt, q, j) * S_DIM + c]);
            }
        }
    } else {
        #pragma unroll
        for (int h = 0; h < 2; ++h) {
            const int c = (2 * hw + h) * 16 + n;
            #pragma unroll
            for (int j = 0; j < 8; ++j) {
                const int k = q * 8 + j;
                float v;
                if (k < N_IN)       v = U_w[(size_t)k * S_DIM + c];
                else if (k == N_IN) v = W_b[c] + U_b[c];
                else                v = 0.f;
                uf[h][j] = f2bf(v);
            }
        }
    }

    // ---- stage a0 into buf0 (exchange layout) ----
    for (int idx = tid; idx < 4 * 16 * 32; idx += 512) {
        const int kt = idx >> 9, r = (idx >> 5) & 15, qj = idx & 31;
        const int s = s_perm(kt, qj >> 3, qj & 7);
        stx[0][kt * KT_STRIDE + r * LPAD + qj] = f2bf(a0[(size_t)(b0 + r) * S_DIM + s]);
    }

    // ---- helper prologue: accU(0), accU(1) into aux[0], aux[1];
    //      rotation regs: slot k holds x(t') with t'%4 == k: x(2),x(3),x(4),x(5) ----
    float4 x0A, x0B, x1A, x1B, x2A, x2B, x3A, x3B;
    if (w >= 4) {
        float4 paA = *(const float4*)(xpA + 0 * N_IN), paB = *(const float4*)(xpB + 0 * N_IN);
        float4 pbA = *(const float4*)(xpA + 1 * N_IN), pbB = *(const float4*)(xpB + 1 * N_IN);
        x2A = *(const float4*)(xpA + 2 * N_IN); x2B = *(const float4*)(xpB + 2 * N_IN);
        x3A = *(const float4*)(xpA + 3 * N_IN); x3B = *(const float4*)(xpB + 3 * N_IN);
        x0A = *(const float4*)(xpA + 4 * N_IN); x0B = *(const float4*)(xpB + 4 * N_IN);
        x1A = *(const float4*)(xpA + 5 * N_IN); x1B = *(const float4*)(xpB + 5 * N_IN);
        f32x4 z = {0.f, 0.f, 0.f, 0.f};
        bf16x8 xf;
        MAKE_XF(xf, paA, paB);
        *(f32x4*)&aux[0][hw][0][l][0] = __builtin_amdgcn_mfma_f32_16x16x32_bf16(uf[0], xf, z, 0, 0, 0);
        *(f32x4*)&aux[0][hw][1][l][0] = __builtin_amdgcn_mfma_f32_16x16x32_bf16(uf[1], xf, z, 0, 0, 0);
        MAKE_XF(xf, pbA, pbB);
        *(f32x4*)&aux[1][hw][0][l][0] = __builtin_amdgcn_mfma_f32_16x16x32_bf16(uf[0], xf, z, 0, 0, 0);
        *(f32x4*)&aux[1][hw][1][l][0] = __builtin_amdgcn_mfma_f32_16x16x32_bf16(uf[1], xf, z, 0, 0, 0);
    }
    block_sync();

    // ---- compute prologue ----
    bf16x8 stOwn, stf1, stf2, stf3;
    f32x4 accU0, accU1;
    if (w < 4) {
        const short* rd = &stx[0][0];
        stOwn = *(const bf16x8*)&rd[((w + 0) & 3) * KT_STRIDE + fragoff];
        stf1  = *(const bf16x8*)&rd[((w + 1) & 3) * KT_STRIDE + fragoff];
        stf2  = *(const bf16x8*)&rd[((w + 2) & 3) * KT_STRIDE + fragoff];
        stf3  = *(const bf16x8*)&rd[((w + 3) & 3) * KT_STRIDE + fragoff];
        accU0 = *(const f32x4*)&aux[0][w][0][l][0];
        accU1 = *(const f32x4*)&aux[0][w][1][l][0];
    }

    // ---- main recurrence.  UU = step phase (0..3), static per unrolled call. ----
#define STEP(PXA, PXB, UU) do {                                                        \
    const int tt = t + (UU);                                                           \
    if (w < 4) {                                                                       \
        __builtin_amdgcn_s_setprio(1);                                                 \
        f32x4 z = {0.f, 0.f, 0.f, 0.f};                                                \
        f32x4 c0a = __builtin_amdgcn_mfma_f32_16x16x32_bf16(wf[0][0], stOwn, accU0, 0, 0, 0); \
        f32x4 c1a = __builtin_amdgcn_mfma_f32_16x16x32_bf16(wf[1][0], stOwn, accU1, 0, 0, 0); \
        c0a = __builtin_amdgcn_mfma_f32_16x16x32_bf16(wf[0][1], stf1, c0a, 0, 0, 0);   \
        c1a = __builtin_amdgcn_mfma_f32_16x16x32_bf16(wf[1][1], stf1, c1a, 0, 0, 0);   \
        f32x4 c0b = __builtin_amdgcn_mfma_f32_16x16x32_bf16(wf[0][2], stf2, z, 0, 0, 0); \
        f32x4 c1b = __builtin_amdgcn_mfma_f32_16x16x32_bf16(wf[1][2], stf2, z, 0, 0, 0); \
        c0b = __builtin_amdgcn_mfma_f32_16x16x32_bf16(wf[0][3], stf3, c0b, 0, 0, 0);   \
        c1b = __builtin_amdgcn_mfma_f32_16x16x32_bf16(wf[1][3], stf3, c1b, 0, 0, 0);   \
        union { unsigned uu[4]; bf16x8 v; } su;                                        \
        su.uu[0] = cvtpk(fmaxf(c0a[0] + c0b[0], 0.f), fmaxf(c0a[1] + c0b[1], 0.f));    \
        su.uu[1] = cvtpk(fmaxf(c0a[2] + c0b[2], 0.f), fmaxf(c0a[3] + c0b[3], 0.f));    \
        su.uu[2] = cvtpk(fmaxf(c1a[0] + c1b[0], 0.f), fmaxf(c1a[1] + c1b[1], 0.f));    \
        su.uu[3] = cvtpk(fmaxf(c1a[2] + c1b[2], 0.f), fmaxf(c1a[3] + c1b[3], 0.f));    \
        stOwn = su.v;                                                                  \
        *(bf16x8*)&stx[((UU) + 1) & 1][w * KT_STRIDE + fragoff] = stOwn;               \
        __builtin_amdgcn_s_setprio(0);                                                 \
    } else {                                                                           \
        /* produce accU(tt+2) into slot ((UU)+2)&3 for wave hw; reload x(tt+6) */      \
        bf16x8 xf_; MAKE_XF(xf_, PXA, PXB);                                            \
        f32x4 z_ = {0.f, 0.f, 0.f, 0.f};                                               \
        f32x4 u0_ = __builtin_amdgcn_mfma_f32_16x16x32_bf16(uf[0], xf_, z_, 0, 0, 0);  \
        f32x4 u1_ = __builtin_amdgcn_mfma_f32_16x16x32_bf16(uf[1], xf_, z_, 0, 0, 0);  \
        *(f32x4*)&aux[((UU) + 2) & 3][hw][0][l][0] = u0_;                              \
        *(f32x4*)&aux[((UU) + 2) & 3][hw][1][l][0] = u1_;                              \
        const int s2_ = (tt + 6 < L_SEQ) ? (tt + 6) : (L_SEQ - 1);                     \
        PXA = *(const float4*)(xpA + (size_t)s2_ * N_IN);                              \
        PXB = *(const float4*)(xpB + (size_t)s2_ * N_IN);                              \
    }                                                                                  \
    block_sync();                                                                      \
    if (w < 4) {                                                                       \
        const short* rd_ = &stx[((UU) + 1) & 1][0];                                    \
        stf1 = *(const bf16x8*)&rd_[((w + 1) & 3) * KT_STRIDE + fragoff];              \
        stf2 = *(const bf16x8*)&rd_[((w + 2) & 3) * KT_STRIDE + fragoff];              \
        stf3 = *(const bf16x8*)&rd_[((w + 3) & 3) * KT_STRIDE + fragoff];              \
        accU0 = *(const f32x4*)&aux[((UU) + 1) & 3][w][0][l][0];                       \
        accU1 = *(const f32x4*)&aux[((UU) + 1) & 3][w][1][l][0];                       \
    }                                                                                  \
} while (0)

    for (int t = 0; t < L_SEQ; t += 4) {
        STEP(x2A, x2B, 0);
        STEP(x3A, x3B, 1);
        STEP(x0A, x0B, 2);
        STEP(x1A, x1B, 3);
    }
#undef STEP
#undef MAKE_XF

    // ---- epilogue: yT = V^T @ aT_L + V_b.  Wave 0 (its li order == physical kt). ----
    if (w == 0) {
        f32x4 acc = {0.f, 0.f, 0.f, 0.f};
        #pragma unroll
        for (int li = 0; li < 4; ++li) {
            bf16x8 vf;
            #pragma unroll
            for (int j = 0; j < 8; ++j)
                vf[j] = (n < M_OUT)
                      ? f2bf(V_w[(size_t)s_perm(li, q, j) * M_OUT + n])
                      : (short)0;
            const bf16x8 stt = (li == 0) ? stOwn : (li == 1) ? stf1 : (li == 2) ? stf2 : stf3;
            acc = __builtin_amdgcn_mfma_f32_16x16x32_bf16(vf, stt, acc, 0, 0, 0);
        }
        #pragma unroll
        for (int j = 0; j < 4; ++j) {
            const int m = 4 * q + j;
            if (m < M_OUT)
                out[(size_t)row * M_OUT + m] = acc[j] + V_b[m];
        }
    }
}

extern "C" void kernel_launch(void* const* d_in, const int* in_sizes, int n_in,
                              void* d_out, int out_size, void* d_ws, size_t ws_size,
                              hipStream_t stream) {
    const float* x   = (const float*)d_in[0];
    const float* a0  = (const float*)d_in[1];
    const float* U_w = (const float*)d_in[2];
    const float* U_b = (const float*)d_in[3];
    const float* W_w = (const float*)d_in[4];
    const float* W_b = (const float*)d_in[5];
    const float* V_w = (const float*)d_in[6];
    const float* V_b = (const float*)d_in[7];
    float* out = (float*)d_out;

    hipLaunchKernelGGL(elman_kernel, dim3(4096 / 16), dim3(512), 0, stream,
                       x, a0, U_w, U_b, W_w, W_b, V_w, V_b, out);
}

// Round 11
// 117.486 us; speedup vs baseline: 1.4902x; 1.4902x over previous
//
#include <hip/hip_runtime.h>
#include <hip/hip_bf16.h>

typedef __attribute__((ext_vector_type(8))) short bf16x8;
typedef __attribute__((ext_vector_type(4))) float f32x4;

#define L_SEQ 512
#define N_IN 12
#define S_DIM 128
#define M_OUT 12
#define LPAD 40           // shorts per n-row (80B -> <=2-way banks)
#define KT_STRIDE (16*LPAD)

// RNE f32->bf16 (cold paths)
__device__ inline short f2bf(float f) {
    union { float f; unsigned u; } q; q.f = f;
    unsigned r = (q.u + 0x7fffu + ((q.u >> 16) & 1u)) >> 16;
    return (short)r;
}
// packed f32x2 -> 2xbf16 (RNE), one VALU op
__device__ inline unsigned cvtpk(float lo, float hi) {
    unsigned r;
    asm("v_cvt_pk_bf16_f32 %0, %1, %2" : "=v"(r) : "v"(lo), "v"(hi));
    return r;
}
// B-slot (kt,q,j) holds state row s = 32kt + 16(j>>2) + 4q + (j&3).
// Same-lane D->B chaining: E2E-verified R4/R5/R7/R8.
__device__ inline int s_perm(int kt, int q, int j) {
    return 32 * kt + 16 * (j >> 2) + 4 * q + (j & 3);
}
// lgkm-only barrier: does NOT drain vmcnt (helpers' x prefetch stays in flight)
__device__ inline void block_sync() {
    asm volatile("s_waitcnt lgkmcnt(0)" ::: "memory");
    __builtin_amdgcn_s_barrier();
}

__global__ __launch_bounds__(512, 1)
void elman_kernel(const float* __restrict__ x,
                  const float* __restrict__ a0,
                  const float* __restrict__ U_w,
                  const float* __restrict__ U_b,
                  const float* __restrict__ W_w,
                  const float* __restrict__ W_b,
                  const float* __restrict__ V_w,
                  const float* __restrict__ V_b,
                  float* __restrict__ out)
{
    __shared__ __align__(16) short stx[2][4 * KT_STRIDE];  // state exchange (ping-pong)
    __shared__ __align__(16) short xr[4][64 * 8];          // xf fragment ring (slot = t&3)

    const int tid  = threadIdx.x;
    const int w    = tid >> 6;        // waves 0..3 compute, 4..7 x-stage helpers
    const int l    = tid & 63;
    const int n    = l & 15;
    const int q    = l >> 4;
    const bool qodd = (q & 1);
    const int b0   = blockIdx.x * 16;
    const int row  = b0 + n;
    const int fragoff = n * LPAD + q * 8;
    const int h    = w & 3;           // helper id

    const float* xpA = x + (size_t)row * L_SEQ * N_IN + (q & 1) * 8;
    const float* xpB = xpA + (qodd ? 0 : 4);

#define MAKE_XF(XF, XA, XB) do {                                                       \
    union { unsigned uu[4]; bf16x8 v; } xu_;                                           \
    xu_.uu[0] = cvtpk(XA.x, XA.y);                                                     \
    xu_.uu[1] = cvtpk(XA.z, XA.w);                                                     \
    xu_.uu[2] = qodd ? 0x00003F80u : cvtpk(XB.x, XB.y);  /* k==12 -> bf16(1.0) */      \
    xu_.uu[3] = qodd ? 0u          : cvtpk(XB.z, XB.w);                                \
    XF = xu_.v;                                                                        \
} while (0)

    // ---- step-invariant fragments ----
    bf16x8 wf[2][4]; bf16x8 uf[2];
    if (w < 4) {
        #pragma unroll
        for (int hh = 0; hh < 2; ++hh) {
            const int c = (2 * w + hh) * 16 + n;
            #pragma unroll
            for (int li = 0; li < 4; ++li) {
                const int kt = (w + li) & 3;
                #pragma unroll
                for (int j = 0; j < 8; ++j)
                    wf[hh][li][j] = f2bf(W_w[(size_t)s_perm(kt, q, j) * S_DIM + c]);
            }
            #pragma unroll
            for (int j = 0; j < 8; ++j) {
                const int k = q * 8 + j;
                float v;
                if (k < N_IN)       v = U_w[(size_t)k * S_DIM + c];
                else if (k == N_IN) v = W_b[c] + U_b[c];   // bias via x-slot k=12 == 1.0
                else                v = 0.f;
                uf[hh][j] = f2bf(v);
            }
        }
    }

    // ---- stage a0 into stx[0] (exchange layout) ----
    for (int idx = tid; idx < 4 * 16 * 32; idx += 512) {
        const int kt = idx >> 9, r = (idx >> 5) & 15, qj = idx & 31;
        const int s = s_perm(kt, qj >> 3, qj & 7);
        stx[0][kt * KT_STRIDE + r * LPAD + qj] = f2bf(a0[(size_t)(b0 + r) * S_DIM + s]);
    }

    // ---- helper prologue ----
    // helper h owns xf slots with t' == h (mod 4); active at loop phase UU=(h+1)&3,
    // staging xf(tt+3) each activation. Pair init: x( h==3 ? 3 : h+4 ).
    // helpers 0,1,2 also prestage xf(0),xf(1),xf(2).
    float4 pA, pB;
    if (w >= 4) {
        if (h < 3) {
            float4 sa = *(const float4*)(xpA + (size_t)h * N_IN);
            float4 sb = *(const float4*)(xpB + (size_t)h * N_IN);
            bf16x8 xf; MAKE_XF(xf, sa, sb);
            *(bf16x8*)&xr[h][l * 8] = xf;
        }
        const int t0 = (h == 3) ? 3 : (h + 4);
        pA = *(const float4*)(xpA + (size_t)t0 * N_IN);
        pB = *(const float4*)(xpB + (size_t)t0 * N_IN);
    }
    block_sync();

    // ---- compute prologue: state(0), xf(0..2), accU(0), c_a(0) partial ----
    bf16x8 stOwnR, stf1, stf2, stf3, xfc_cur, xfc_next;
    f32x4 accU0, accU1, c0a, c1a;
    if (w < 4) {
        const short* rd = &stx[0][0];
        stOwnR = *(const bf16x8*)&rd[((w + 0) & 3) * KT_STRIDE + fragoff];
        stf1   = *(const bf16x8*)&rd[((w + 1) & 3) * KT_STRIDE + fragoff];
        stf2   = *(const bf16x8*)&rd[((w + 2) & 3) * KT_STRIDE + fragoff];
        stf3   = *(const bf16x8*)&rd[((w + 3) & 3) * KT_STRIDE + fragoff];
        bf16x8 xf0 = *(const bf16x8*)&xr[0][l * 8];
        xfc_cur    = *(const bf16x8*)&xr[1][l * 8];   // xf(1)
        xfc_next   = *(const bf16x8*)&xr[2][l * 8];   // xf(2)
        f32x4 z = {0.f, 0.f, 0.f, 0.f};
        accU0 = __builtin_amdgcn_mfma_f32_16x16x32_bf16(uf[0], xf0, z, 0, 0, 0);
        accU1 = __builtin_amdgcn_mfma_f32_16x16x32_bf16(uf[1], xf0, z, 0, 0, 0);
        c0a = __builtin_amdgcn_mfma_f32_16x16x32_bf16(wf[0][0], stOwnR, accU0, 0, 0, 0);
        c1a = __builtin_amdgcn_mfma_f32_16x16x32_bf16(wf[1][0], stOwnR, accU1, 0, 0, 0);
    }

    // ---- main recurrence.  body t: finish step t, pack state(t+1), pre-issue
    //      own MFMAs of step t+1; helpers stage xf(tt+3). ----
#define STEP(UU) do {                                                                  \
    const int tt = t + (UU);                                                           \
    if (w < 4) {                                                                       \
        __builtin_amdgcn_s_setprio(1);                                                 \
        f32x4 z = {0.f, 0.f, 0.f, 0.f};                                                \
        /* head: accU(tt+1) from xfc_cur = xf(tt+1) (read 1.5 epochs ago) */           \
        accU0 = __builtin_amdgcn_mfma_f32_16x16x32_bf16(uf[0], xfc_cur, z, 0, 0, 0);   \
        accU1 = __builtin_amdgcn_mfma_f32_16x16x32_bf16(uf[1], xfc_cur, z, 0, 0, 0);   \
        /* finish step tt */                                                           \
        c0a = __builtin_amdgcn_mfma_f32_16x16x32_bf16(wf[0][1], stf1, c0a, 0, 0, 0);   \
        c1a = __builtin_amdgcn_mfma_f32_16x16x32_bf16(wf[1][1], stf1, c1a, 0, 0, 0);   \
        f32x4 c0b = __builtin_amdgcn_mfma_f32_16x16x32_bf16(wf[0][2], stf2, z, 0, 0, 0); \
        f32x4 c1b = __builtin_amdgcn_mfma_f32_16x16x32_bf16(wf[1][2], stf2, z, 0, 0, 0); \
        c0b = __builtin_amdgcn_mfma_f32_16x16x32_bf16(wf[0][3], stf3, c0b, 0, 0, 0);   \
        c1b = __builtin_amdgcn_mfma_f32_16x16x32_bf16(wf[1][3], stf3, c1b, 0, 0, 0);   \
        /* pack state(tt+1) */                                                         \
        union { unsigned uu[4]; bf16x8 v; } su;                                        \
        su.uu[0] = cvtpk(fmaxf(c0a[0] + c0b[0], 0.f), fmaxf(c0a[1] + c0b[1], 0.f));    \
        su.uu[1] = cvtpk(fmaxf(c0a[2] + c0b[2], 0.f), fmaxf(c0a[3] + c0b[3], 0.f));    \
        su.uu[2] = cvtpk(fmaxf(c1a[0] + c1b[0], 0.f), fmaxf(c1a[1] + c1b[1], 0.f));    \
        su.uu[3] = cvtpk(fmaxf(c1a[2] + c1b[2], 0.f), fmaxf(c1a[3] + c1b[3], 0.f));    \
        stOwnR = su.v;                                                                 \
        /* pre-barrier: own-tile MFMAs of step tt+1 (all-register operands) */         \
        c0a = __builtin_amdgcn_mfma_f32_16x16x32_bf16(wf[0][0], stOwnR, accU0, 0, 0, 0); \
        c1a = __builtin_amdgcn_mfma_f32_16x16x32_bf16(wf[1][0], stOwnR, accU1, 0, 0, 0); \
        *(bf16x8*)&stx[(tt + 1) & 1][w * KT_STRIDE + fragoff] = stOwnR;                \
        xfc_cur = xfc_next;                                                            \
        __builtin_amdgcn_s_setprio(0);                                                 \
    } else {                                                                           \
        /* helper (UU+3)&3 stages xf(tt+3) from its pair, reloads x(tt+7) */           \
        if (h == (((UU) + 3) & 3)) {                                                   \
            bf16x8 xf_; MAKE_XF(xf_, pA, pB);                                          \
            *(bf16x8*)&xr[h][l * 8] = xf_;                                             \
            const int s2_ = (tt + 7 < L_SEQ) ? (tt + 7) : (L_SEQ - 1);                 \
            pA = *(const float4*)(xpA + (size_t)s2_ * N_IN);                           \
            pB = *(const float4*)(xpB + (size_t)s2_ * N_IN);                           \
        }                                                                              \
    }                                                                                  \
    block_sync();                                                                      \
    if (w < 4) {                                                                       \
        const short* rd_ = &stx[(tt + 1) & 1][0];                                      \
        stf1 = *(const bf16x8*)&rd_[((w + 1) & 3) * KT_STRIDE + fragoff];              \
        stf2 = *(const bf16x8*)&rd_[((w + 2) & 3) * KT_STRIDE + fragoff];              \
        stf3 = *(const bf16x8*)&rd_[((w + 3) & 3) * KT_STRIDE + fragoff];              \
        xfc_next = *(const bf16x8*)&xr[(((UU) + 3) & 3)][l * 8];   /* xf(tt+3) */      \
    }                                                                                  \
} while (0)

    for (int t = 0; t < L_SEQ; t += 4) {
        STEP(0);
        STEP(1);
        STEP(2);
        STEP(3);
    }
#undef STEP
#undef MAKE_XF

    // ---- epilogue: yT = V^T @ aT_L + V_b.  Wave 0 (its li order == physical kt). ----
    if (w == 0) {
        f32x4 acc = {0.f, 0.f, 0.f, 0.f};
        #pragma unroll
        for (int li = 0; li < 4; ++li) {
            bf16x8 vf;
            #pragma unroll
            for (int j = 0; j < 8; ++j)
                vf[j] = (n < M_OUT)
                      ? f2bf(V_w[(size_t)s_perm(li, q, j) * M_OUT + n])
                      : (short)0;
            const bf16x8 stt = (li == 0) ? stOwnR : (li == 1) ? stf1 : (li == 2) ? stf2 : stf3;
            acc = __builtin_amdgcn_mfma_f32_16x16x32_bf16(vf, stt, acc, 0, 0, 0);
        }
        #pragma unroll
        for (int j = 0; j < 4; ++j) {
            const int m = 4 * q + j;
            if (m < M_OUT)
                out[(size_t)row * M_OUT + m] = acc[j] + V_b[m];
        }
    }
}

extern "C" void kernel_launch(void* const* d_in, const int* in_sizes, int n_in,
                              void* d_out, int out_size, void* d_ws, size_t ws_size,
                              hipStream_t stream) {
    const float* x   = (const float*)d_in[0];
    const float* a0  = (const float*)d_in[1];
    const float* U_w = (const float*)d_in[2];
    const float* U_b = (const float*)d_in[3];
    const float* W_w = (const float*)d_in[4];
    const float* W_b = (const float*)d_in[5];
    const float* V_w = (const float*)d_in[6];
    const float* V_b = (const float*)d_in[7];
    float* out = (float*)d_out;

    hipLaunchKernelGGL(elman_kernel, dim3(4096 / 16), dim3(512), 0, stream,
                       x, a0, U_w, U_b, W_w, W_b, V_w, V_b, out);
}